// Round 9
// baseline (83.244 us; speedup 1.0000x reference)
//
#include <hip/hip_runtime.h>
#include <math.h>

#define NB      25200
#define NB4     6300          // NB/4 exactly
#define THREADS 1024
#define KV      7             // 7*1024 float4 = 28672 elems >= 25200
#define NBINS   512
#define CAP     128
#define MAXOUT  100
#define CONF    0.25f
#define PRE     0.98f         // pre-filter: only scores > PRE enter the histogram
#define IOU_T   0.45f
#define NWAVE   16
#define ITEMS_FB 25           // fallback: 1024*25 = 25600 >= NB

typedef unsigned long long u64;
typedef unsigned int u32;

__device__ __forceinline__ bool better(float sa_, int ia_, float sb_, int ib_) {
    return (sb_ > sa_) || (sb_ == sa_ && ib_ < ia_);
}

__global__ __launch_bounds__(THREADS, 1)
void nms_all(const float* __restrict__ boxes,
             const float* __restrict__ scores,
             float* __restrict__ out,
             float* __restrict__ ws_live)      // fallback-only global scratch (25600 floats)
{
    const int tid  = threadIdx.x;
    const int lane = tid & 63;
    const int wv   = tid >> 6;

    __shared__ int    hist[NBINS];
    __shared__ u64    keys[CAP];
    __shared__ float4 sbv[CAP];
    __shared__ float  ss[CAP];
    __shared__ float4 cand_b[CAP];
    __shared__ float  cand_s[CAP];
    __shared__ int    cand_i[CAP];
    __shared__ u64    mat[CAP][2];       // suppression bits (128 cols), j > i only
    __shared__ int    prank[8][CAP];
    __shared__ int    klist[MAXOUT];
    __shared__ int    s_cnt, s_tbin, s_pack, s_kept;
    __shared__ float  red_v[NWAVE];
    __shared__ int    red_i[NWAVE];

    const float4* b4 = (const float4*)boxes;
    const float4* s4 = (const float4*)scores;
    const float binscale = (float)NBINS / (1.0f - PRE);

    // ---- A0: issue all score loads first (28 regs/thread), then init LDS ----
    float4 sc[KV];
#pragma unroll
    for (int k = 0; k < KV; ++k) {
        const int v = k * THREADS + tid;
        sc[k] = (v < NB4) ? s4[v] : make_float4(-1.f, -1.f, -1.f, -1.f);
    }
    if (tid < NBINS) hist[tid] = 0;
    if (tid == 0) { s_cnt = 0; s_pack = 0; }
    __syncthreads();

    // ---- A1: register counting; LDS atomics only for the ~2% above PRE ----
    int pack = 0;                        // (count>CONF)<<16 | (count>PRE)
#pragma unroll
    for (int k = 0; k < KV; ++k) {
        const float el[4] = {sc[k].x, sc[k].y, sc[k].z, sc[k].w};
#pragma unroll
        for (int e = 0; e < 4; ++e) {
            const float s = el[e];
            if (s > CONF) pack += 0x10000;
            if (s > PRE) {
                pack += 1;
                int b = (int)((s - PRE) * binscale);
                b = b < 0 ? 0 : (b > NBINS - 1 ? NBINS - 1 : b);
                atomicAdd(&hist[b], 1);
            }
        }
    }
#pragma unroll
    for (int off = 1; off < 64; off <<= 1) pack += __shfl_xor(pack, off);
    if (lane == 0) atomicAdd(&s_pack, pack);
    __syncthreads();
    const int total_conf = s_pack >> 16;

    // ---- A2: wave-0 suffix scan over 512 bins -> threshold bin ----
    if (tid < 64) {
        int h[8], ls[8];
#pragma unroll
        for (int r = 0; r < 8; ++r) h[r] = hist[lane * 8 + r];
        int acc = 0;
#pragma unroll
        for (int r = 7; r >= 0; --r) { acc += h[r]; ls[r] = acc; }
        u32 inc = (u32)acc;              // inclusive suffix over lane chunks
#pragma unroll
        for (int off = 1; off < 64; off <<= 1) {
            const u32 t = __shfl_down(inc, off);
            if (lane + off < 64) inc += t;
        }
        const int excl = (int)inc - acc;
        int loc = NBINS;                 // smallest bin with suffix <= CAP (0 if hist empty)
#pragma unroll
        for (int r = 7; r >= 0; --r) { if (ls[r] + excl <= CAP) loc = lane * 8 + r; }
#pragma unroll
        for (int off = 32; off >= 1; off >>= 1) {
            const int t = __shfl_xor(loc, off);
            if (t < loc) loc = t;
        }
        if (lane == 0) s_tbin = loc;
    }
    __syncthreads();
    const int tbin = s_tbin;

    // ---- A3: compaction; per-lane +1 LDS atomics ----
#pragma unroll
    for (int k = 0; k < KV; ++k) {
        const int v = k * THREADS + tid;
        const float el[4] = {sc[k].x, sc[k].y, sc[k].z, sc[k].w};
#pragma unroll
        for (int e = 0; e < 4; ++e) {
            const float s = el[e];
            bool pred = false;
            if (s > PRE) {
                int b = (int)((s - PRE) * binscale);
                b = b < 0 ? 0 : (b > NBINS - 1 ? NBINS - 1 : b);
                pred = (b >= tbin);
            }
            if (pred) {
                const int pos = atomicAdd(&s_cnt, 1);
                if (pos < CAP) {
                    const int i = 4 * v + e;
                    cand_s[pos] = s; cand_i[pos] = i; cand_b[pos] = b4[i];
                }
            }
        }
    }
    __syncthreads();
    const int M0 = s_cnt;
    const int M  = (M0 > CAP) ? CAP : M0;

    // ---- B1: sort keys (score desc, orig idx asc); sentinels above all real keys ----
    float cs = 0.f; int ci = 0; float4 cb = make_float4(0.f, 0.f, 0.f, 0.f);
    if (tid < CAP) {
        if (tid < M) { cs = cand_s[tid]; ci = cand_i[tid]; cb = cand_b[tid]; }
        keys[tid] = (tid < M)
            ? (((u64)(~__float_as_uint(cs)) << 32) | (u64)(u32)ci)
            : (0xFFFFFFFF00000000ULL | (u64)tid);
    }
    __syncthreads();

    // ---- B2: rank by counting, 8 chunks x 16 keys, batched broadcast loads ----
    {
        const int key   = tid & (CAP - 1);
        const int chunk = tid >> 7;      // 0..7
        const u64 myk   = keys[key];
        u64 kb[16];
#pragma unroll
        for (int q = 0; q < 16; ++q) kb[q] = keys[chunk * 16 + q];
        int r = 0;
#pragma unroll
        for (int q = 0; q < 16; ++q) r += (kb[q] < myk) ? 1 : 0;
        prank[chunk][key] = r;
    }
    __syncthreads();
    if (tid < CAP && tid < M) {
        int rank = 0;
#pragma unroll
        for (int c = 0; c < 8; ++c) rank += prank[c][tid];
        sbv[rank] = cb;
        ss[rank]  = cs;
    }
    __syncthreads();

    // ---- B4: ballot-row bitmatrix; 16 waves = 2 words x 8 row-groups of 16 ----
    {
        const int word = wv & 1;
        const int rb   = (wv >> 1) * 16;
        const int jidx = (word << 6) + lane;
        const float4 bj = sbv[jidx];     // garbage if >= M (pred-masked)
        const float  aj = fmaxf(bj.z - bj.x, 0.f) * fmaxf(bj.w - bj.y, 0.f);
        const bool   jv = (jidx < M);
        for (int ii = 0; ii < 16; ii += 4) {
            float4 bi[4];
#pragma unroll
            for (int q = 0; q < 4; ++q) bi[q] = sbv[rb + ii + q];   // broadcast, 4 in flight
#pragma unroll
            for (int q = 0; q < 4; ++q) {
                const int irow = rb + ii + q;
                const float ai = fmaxf(bi[q].z - bi[q].x, 0.f) * fmaxf(bi[q].w - bi[q].y, 0.f);
                const float ltx = fmaxf(bi[q].x, bj.x);
                const float lty = fmaxf(bi[q].y, bj.y);
                const float rbx = fminf(bi[q].z, bj.z);
                const float rby = fminf(bi[q].w, bj.w);
                const float w_ = fmaxf(rbx - ltx, 0.f);
                const float h_ = fmaxf(rby - lty, 0.f);
                const float inter = w_ * h_;
                const float den = ((ai + aj) - inter) + 1e-9f;      // ref assoc order
                const bool pred = jv && (irow < M) && (jidx > irow) && (inter > IOU_T * den);
                const u64 bal = __ballot(pred);
                if (lane == 0) mat[irow][word] = bal;
            }
        }
    }
    __syncthreads();

    // ---- B5: wave-parallel greedy scan, rows in registers, no LDS in loop ----
    if (wv == 0) {
        const int r0i = 2 * lane, r1i = 2 * lane + 1;
        const u64 m00 = mat[r0i][0], m01 = mat[r0i][1];    // one b128 per lane
        const u64 m10 = mat[r1i][0], m11 = mat[r1i][1];
        u32 alive = ((r0i < M) ? 1u : 0u) | ((r1i < M) ? 2u : 0u);
        int kept = 0;
        while (kept < MAXOUT) {
            const u64 bal = __ballot(alive != 0u);
            if (!bal) break;
            const int ldr = __ffsll(bal) - 1;              // lowest alive row's lane
            const u32 la  = __shfl(alive, ldr);
            const int sub = (la & 1u) ? 0 : 1;             // leader's first alive row
            const int row = 2 * ldr + sub;
            const u64 ra  = __shfl(sub ? m10 : m00, ldr);  // leader's row words (uniform sub)
            const u64 rb  = __shfl(sub ? m11 : m01, ldr);
            if (lane == 0) klist[kept] = row;
            ++kept;
            if (kept == MAXOUT) break;
            u32 kill = 0;                                  // suppression for my two rows
            kill |= (u32)(((r0i < 64) ? (ra >> r0i) : (rb >> (r0i - 64))) & 1ULL);
            kill |= (u32)(((r1i < 64) ? (ra >> r1i) : (rb >> (r1i - 64))) & 1ULL) << 1;
            alive &= ~kill;
            if (lane == ldr) alive &= ~(1u << sub);        // kept box leaves the pool
        }
        if (lane == 0) s_kept = kept;
    }
    __syncthreads();

    // ---- epilogue / fallback decision ----
    const int kept = s_kept;
    const bool need_fb = (M0 > CAP) || (kept < MAXOUT && M0 < total_conf);
    if (!need_fb) {                                   // block-uniform branch
        if (tid < MAXOUT) {
            float4 bb = make_float4(0.f, 0.f, 0.f, 0.f);
            float  sc_ = 0.f;
            if (tid < kept) { const int j = klist[tid]; bb = sbv[j]; sc_ = ss[j]; }
            ((float4*)out)[tid] = bb;
            out[4*MAXOUT + tid] = sc_;
        }
        return;
    }

    // ---------------- exact full fallback via global scratch (never on bench data) ----------------
    if (tid < 25600 - NB) ws_live[NB + tid] = -INFINITY;
    for (int k = 0; k < ITEMS_FB; ++k) {
        const int i = k * THREADS + tid;
        if (i < NB) {
            const float s0 = scores[i];
            ws_live[i] = (s0 > CONF) ? s0 : -INFINITY;
        }
    }
    __syncthreads();
    for (int r = 0; r < MAXOUT; ++r) {
        float lm = -INFINITY; int li = 0x7fffffff;
        for (int k = 0; k < ITEMS_FB; ++k) {
            const int i = k * THREADS + tid;
            const float v = ws_live[i];
            if (v > lm) { lm = v; li = i; }           // ascending scan: ties -> lower i
        }
        float rv = lm; int ri = li;
#pragma unroll
        for (int off = 32; off >= 1; off >>= 1) {
            const float ov = __shfl_xor(rv, off);
            const int   oi = __shfl_xor(ri, off);
            if (better(rv, ri, ov, oi)) { rv = ov; ri = oi; }
        }
        __syncthreads();
        if (lane == 0) { red_v[wv] = rv; red_i[wv] = ri; }
        __syncthreads();
        float wval = red_v[0]; int widx = red_i[0];
#pragma unroll
        for (int j = 1; j < NWAVE; ++j) {
            const float v = red_v[j]; const int i2 = red_i[j];
            if (better(wval, widx, v, i2)) { wval = v; widx = i2; }
        }
        if (!(wval > -1e38f)) {
            if (tid == 0) {
                out[4*r+0]=0.f; out[4*r+1]=0.f; out[4*r+2]=0.f; out[4*r+3]=0.f;
                out[4*MAXOUT + r] = 0.f;
            }
            continue;
        }
        const float4 wb = b4[widx];
        if (tid == 0) {
            out[4*r+0]=wb.x; out[4*r+1]=wb.y; out[4*r+2]=wb.z; out[4*r+3]=wb.w;
            out[4*MAXOUT + r] = wval;
        }
        const float warea = fmaxf(wb.z - wb.x, 0.f) * fmaxf(wb.w - wb.y, 0.f);
        for (int k = 0; k < ITEMS_FB; ++k) {
            const int i = k * THREADS + tid;
            if (i < NB) {
                const float4 bb = b4[i];
                const float area = fmaxf(bb.z - bb.x, 0.f) * fmaxf(bb.w - bb.y, 0.f);
                const float ltx = fmaxf(bb.x, wb.x);
                const float lty = fmaxf(bb.y, wb.y);
                const float rbx = fminf(bb.z, wb.z);
                const float rby = fminf(bb.w, wb.w);
                const float w  = fmaxf(rbx - ltx, 0.f);
                const float h  = fmaxf(rby - lty, 0.f);
                const float inter = w * h;
                const float den = ((warea + area) - inter) + 1e-9f;
                if (inter > IOU_T * den || i == widx) ws_live[i] = -INFINITY;
            }
        }
        __syncthreads();
    }
}

extern "C" void kernel_launch(void* const* d_in, const int* in_sizes, int n_in,
                              void* d_out, int out_size, void* d_ws, size_t ws_size,
                              hipStream_t stream) {
    const float* boxes  = (const float*)d_in[0];
    const float* scores = (const float*)d_in[1];
    float* out = (float*)d_out;
    nms_all<<<dim3(1), dim3(THREADS), 0, stream>>>(boxes, scores, out, (float*)d_ws);
}